// Round 1
// baseline (195.633 us; speedup 1.0000x reference)
//
#include <hip/hip_runtime.h>

#define TT 25000
#define BB 2
#define CC 128
#define NN (BB*TT)   // 50000 nodes
#define NB ((NN + 255) / 256)  // 196 scan blocks
#define NBPAD 256
#define GEMMB ((NN + 63) / 64) // 782 gemm blocks

typedef __attribute__((ext_vector_type(8))) short bf16x8;
typedef __attribute__((ext_vector_type(4))) float f32x4;

__device__ inline unsigned short f2bf(float f) {
    unsigned int u = __float_as_uint(f);
    u += 0x7FFF + ((u >> 16) & 1);          // round-to-nearest-even
    return (unsigned short)(u >> 16);
}
__device__ inline float bfhi(unsigned int v) { return __uint_as_float(v << 16); }
__device__ inline float bflo(unsigned int v) { return __uint_as_float(v & 0xFFFF0000u); }

// ---------------- degree count + per-edge sequence number + per-scan-block sums --------
// Fuses old k_bsum: LDS histogram of deg contributions per 256-node scan block,
// flushed with one global atomicAdd per bucket per block. bsum must be pre-zeroed
// (covered by the single memset that also zeroes deg).
__global__ __launch_bounds__(256) void k_deg(const int* __restrict__ dst, int E,
                                             int* __restrict__ deg,
                                             int* __restrict__ eseq,
                                             int* __restrict__ bsum) {
    __shared__ int hist[NB];
    for (int i = threadIdx.x; i < NB; i += 256) hist[i] = 0;
    __syncthreads();

    int base = blockIdx.x * 1024 + threadIdx.x;
    int d[4]; bool ok[4];
#pragma unroll
    for (int u = 0; u < 4; ++u) {
        int i = base + u * 256;
        ok[u] = (i < E);
        d[u] = ok[u] ? dst[i] : 0;
    }
#pragma unroll
    for (int u = 0; u < 4; ++u)
        if (ok[u]) {
            eseq[base + u * 256] = atomicAdd(&deg[d[u]], 1);
            atomicAdd(&hist[d[u] >> 8], 1);
        }
    __syncthreads();
    for (int i = threadIdx.x; i < NB; i += 256) {
        int v = hist[i];
        if (v) atomicAdd(&bsum[i], v);
    }
}

// ---------------- scan pass 2: block prefix + local scan + dinv ----------------
__global__ __launch_bounds__(256) void k_scan2(const int* __restrict__ deg,
                                               const int* __restrict__ bsum,
                                               int* __restrict__ off,
                                               float* __restrict__ dinv) {
    __shared__ int part[256];
    __shared__ int bpref;
    int tid = threadIdx.x;
    int i = blockIdx.x * 256 + tid;

    part[tid] = (tid < NB && tid < blockIdx.x) ? bsum[tid] : 0;
    __syncthreads();
#pragma unroll
    for (int o = 128; o > 0; o >>= 1) {
        if (tid < o) part[tid] += part[tid + o];
        __syncthreads();
    }
    if (tid == 0) bpref = part[0];
    __syncthreads();
    int base = bpref;
    __syncthreads();

    int v = (i < NN) ? deg[i] : 0;
    part[tid] = v;
    __syncthreads();
#pragma unroll
    for (int o = 1; o < 256; o <<= 1) {
        int u = (tid >= o) ? part[tid - o] : 0;
        __syncthreads();
        part[tid] += u;
        __syncthreads();
    }
    int incl = part[tid];
    if (i < NN) {
        off[i]  = base + incl - v;                  // exclusive
        dinv[i] = rsqrtf((float)(v + 1));
    }
    if (i == NN - 1) off[NN] = base + incl;         // == E
}

// ---------------- fused: MFMA GEMM blocks [0,GEMMB) + CSR-fill blocks [GEMMB, ...) ----
// Both depend only on k_scan2 (off/dinv) and are mutually independent, so one
// launch lets the memory-only fill overlap the compute/LDS-heavy gemm.
__global__ __launch_bounds__(256) void k_fg(const float* __restrict__ x,
                                            const float* __restrict__ W,
                                            const float* __restrict__ dinv,
                                            unsigned short* __restrict__ h,
                                            const int* __restrict__ src,
                                            const int* __restrict__ dst, int E,
                                            const int* __restrict__ off,
                                            const int* __restrict__ eseq,
                                            int* __restrict__ csr_src) {
    __shared__ __align__(16) unsigned short a_lds[4][4][64][8];  // 16 KB
    __shared__ __align__(16) unsigned short b_lds[8][4][64][8];  // 32 KB
    int bx = blockIdx.x;
    if (bx >= GEMMB) {
        // ---- CSR fill: atomic-free scatter ----
        int i = (bx - GEMMB) * 256 + threadIdx.x;
        if (i < E) {
            int d = dst[i];
            csr_src[off[d] + eseq[i]] = src[i];
        }
        return;
    }

    // ---- GEMM: 64 nodes x 128 oc, h'[n][oc] = dinv[n] * sum_c x[n][c]*W[c][oc] ----
    int tid = threadIdx.x;
    int n0 = bx * 64;

    // stage A (x -> bf16, fragment order)
    {
        int m = tid & 63;
        int n = n0 + m;
        bool ok = (n < NN);
        int b = 0, t = 0;
        if (ok) { b = n / TT; t = n - b * TT; }
        const float* xp = x + ((size_t)b * CC) * TT + t;
        int mt = m >> 4, lm = m & 15;
#pragma unroll
        for (int p = 0; p < 4; ++p) {
            int kg = (tid >> 6) + p * 4;            // 0..15, wave-uniform
            unsigned short tmp[8];
#pragma unroll
            for (int j = 0; j < 8; ++j) {
                float v = ok ? xp[(size_t)(kg * 8 + j) * TT] : 0.f;
                tmp[j] = f2bf(v);
            }
            int kk = kg >> 2, q = kg & 3;
            *(bf16x8*)&a_lds[mt][kk][lm | (q << 4)][0] = *(bf16x8*)tmp;
        }
    }
    // stage B (W -> bf16, fragment order)
    {
        int nc = tid & 127;
        int nt = nc >> 4, ln = nc & 15;
#pragma unroll
        for (int p = 0; p < 8; ++p) {
            int kg = (tid >> 7) + p * 2;            // 0..15
            unsigned short tmp[8];
#pragma unroll
            for (int j = 0; j < 8; ++j)
                tmp[j] = f2bf(W[(kg * 8 + j) * CC + nc]);
            int kk = kg >> 2, q = kg & 3;
            *(bf16x8*)&b_lds[nt][kk][ln | (q << 4)][0] = *(bf16x8*)tmp;
        }
    }
    __syncthreads();

    int lane = tid & 63;
    int w = tid >> 6;
    f32x4 acc[8];
#pragma unroll
    for (int nt = 0; nt < 8; ++nt) acc[nt] = (f32x4){0.f, 0.f, 0.f, 0.f};
#pragma unroll
    for (int kk = 0; kk < 4; ++kk) {
        bf16x8 a = *(const bf16x8*)&a_lds[w][kk][lane][0];
#pragma unroll
        for (int nt = 0; nt < 8; ++nt) {
            bf16x8 bb = *(const bf16x8*)&b_lds[nt][kk][lane][0];
            acc[nt] = __builtin_amdgcn_mfma_f32_16x16x32_bf16(a, bb, acc[nt], 0, 0, 0);
        }
    }

    // epilogue: scale by dinv, bf16, store
    int q = lane >> 4, col = lane & 15;
    int nodebase = n0 + w * 16 + q * 4;
    float di[4];
#pragma unroll
    for (int r = 0; r < 4; ++r) {
        int nn = nodebase + r;
        di[r] = (nn < NN) ? dinv[nn] : 0.f;
    }
#pragma unroll
    for (int nt = 0; nt < 8; ++nt) {
#pragma unroll
        for (int r = 0; r < 4; ++r) {
            int nn = nodebase + r;
            if (nn < NN)
                h[(size_t)nn * CC + nt * 16 + col] = f2bf(di[r] * acc[nt][r]);
        }
    }
}

// ---------------- fused aggregation + transpose ----------------
// Block = 8 waves (512 thr), 32 consecutive nodes (wave w owns nodes w*4..w*4+3,
// processed sequentially with the identical per-node accumulation order as before).
// Results land in an LDS [t][ch] tile, then are written straight to out[b][ch][t]
// in fp32 (coalesced 128B rows per channel) — no agg16 round-trip, no final
// bf16 rounding.
__global__ __launch_bounds__(512) void k_aggt(const unsigned int* __restrict__ hb,
                                              const int* __restrict__ off,
                                              const int* __restrict__ csr_src,
                                              const float* __restrict__ dinv,
                                              const float* __restrict__ bias,
                                              float* __restrict__ out) {
    __shared__ float tile[32][129];                 // 16.5 KB, +1 pad
    int lane = threadIdx.x & 63;
    int w    = threadIdx.x >> 6;                    // 0..7
    int n0   = blockIdx.x * 32;
    const float2 bb = ((const float2*)bias)[lane];

#pragma unroll
    for (int r = 0; r < 4; ++r) {
        int lt = w * 4 + r;
        int n = n0 + lt;
        if (n < NN) {
            float ax = 0.f, ay = 0.f;
            int e0 = off[n], e1 = off[n + 1];

            for (int c0 = e0; c0 < e1; c0 += 64) {
                int cnt = e1 - c0; if (cnt > 64) cnt = 64;
                int li = lane < cnt ? lane : cnt - 1;
                int iv = csr_src[c0 + li];          // 64 indices, one coalesced load
                int j = 0;
                for (; j + 16 <= cnt; j += 16) {
                    int s[16];
#pragma unroll
                    for (int u = 0; u < 16; ++u) s[u] = __shfl(iv, j + u, 64);
                    unsigned int v[16];
#pragma unroll
                    for (int u = 0; u < 16; ++u) v[u] = hb[(size_t)s[u] * 64 + lane];
#pragma unroll
                    for (int u = 0; u < 16; ++u) { ax += bfhi(v[u]); ay += bflo(v[u]); }
                }
                for (; j + 4 <= cnt; j += 4) {
                    int s[4];
#pragma unroll
                    for (int u = 0; u < 4; ++u) s[u] = __shfl(iv, j + u, 64);
                    unsigned int v[4];
#pragma unroll
                    for (int u = 0; u < 4; ++u) v[u] = hb[(size_t)s[u] * 64 + lane];
#pragma unroll
                    for (int u = 0; u < 4; ++u) { ax += bfhi(v[u]); ay += bflo(v[u]); }
                }
                for (; j < cnt; ++j) {
                    int s = __shfl(iv, j, 64);
                    unsigned int v = hb[(size_t)s * 64 + lane];
                    ax += bfhi(v); ay += bflo(v);
                }
            }

            unsigned int hv = hb[(size_t)n * 64 + lane];    // self loop
            ax += bfhi(hv);
            ay += bflo(hv);
            float di = dinv[n];
            float rx = fmaxf(fmaf(di, ax, bb.x), 0.f);
            float ry = fmaxf(fmaf(di, ay, bb.y), 0.f);
            tile[lt][2 * lane]     = rx;            // 2-way bank alias: free
            tile[lt][2 * lane + 1] = ry;
        }
    }
    __syncthreads();

    // write-out: 512 threads cover 32 t x 128 ch; each 32-thread group writes one
    // contiguous 128B row of out for a fixed channel.
    int tx = threadIdx.x & 31;                      // local t
    int cg = threadIdx.x >> 5;                      // 0..15
    int n = n0 + tx;
    if (n < NN) {
        int b = n / TT, t = n - b * TT;
#pragma unroll
        for (int i = 0; i < 8; ++i) {
            int ch = cg + i * 16;                   // 0..127
            out[((size_t)b * CC + ch) * TT + t] = tile[tx][ch];
        }
    }
}

extern "C" void kernel_launch(void* const* d_in, const int* in_sizes, int n_in,
                              void* d_out, int out_size, void* d_ws, size_t ws_size,
                              hipStream_t stream) {
    const float* x    = (const float*)d_in[0];
    const float* W    = (const float*)d_in[1];
    const float* bias = (const float*)d_in[2];
    const int*   ei   = (const int*)d_in[3];
    int E = in_sizes[3] / 2;
    const int* src = ei;
    const int* dst = ei + E;
    float* out = (float*)d_out;

    char* ws = (char*)d_ws;
    size_t o = 0;
    unsigned short* h = (unsigned short*)(ws + o); o += (size_t)NN * CC * 2;  // 12.8 MB
    int*   deg  = (int*)  (ws + o); o += (size_t)NN * 4;
    int*   bsum = (int*)  (ws + o); o += (size_t)NBPAD * 4;   // adjacent to deg: one memset
    float* dinv = (float*)(ws + o); o += (size_t)NN * 4;
    int*   off  = (int*)  (ws + o); o += (size_t)(NN + 1) * 4 + 12;
    int*   eseq = (int*)  (ws + o); o += (size_t)E * 4;
    int*   csrs = (int*)  (ws + o); o += (size_t)E * 4;

    hipMemsetAsync(deg, 0, (size_t)(NN + NBPAD) * 4, stream);

    int fb = (E + 255) / 256;
    k_deg  <<<(E + 1023) / 1024, 256, 0, stream>>>(dst, E, deg, eseq, bsum);
    k_scan2<<<NB, 256, 0, stream>>>(deg, bsum, off, dinv);
    k_fg   <<<GEMMB + fb, 256, 0, stream>>>(x, W, dinv, h, src, dst, E, off, eseq, csrs);
    k_aggt <<<(NN + 31) / 32, 512, 0, stream>>>((const unsigned int*)h, off, csrs, dinv, bias, out);
}